// Round 2
// baseline (515.684 us; speedup 1.0000x reference)
//
#include <hip/hip_runtime.h>
#include <stdint.h>

// Problem constants
#define NB 4096
#define NT 512
#define OT 513
#define TOTE (NB*OT)          // 2101248 elements per output matrix
#define LOSSOFF (2*TOTE)      // diff_loss slot

typedef float  f32x4 __attribute__((ext_vector_type(4)));
typedef __fp16 f16x8 __attribute__((ext_vector_type(8)));
typedef __fp16 f16x2 __attribute__((ext_vector_type(2)));

#define MFMA(A,B,C) __builtin_amdgcn_mfma_f32_16x16x32_f16((A),(B),(C),0,0,0)

// Barrier that drains LDS only (no vmcnt(0) drain -> global stores stay in flight)
__device__ __forceinline__ void wg_barrier() {
  asm volatile("s_waitcnt lgkmcnt(0)\n\ts_barrier" ::: "memory");
}

__device__ __forceinline__ float fast_tanh(float x) {
  // tanh(x) = 1 - 2/(1+exp(2x)); exp via exp2. Accurate to ~1e-7, saturates safely.
  float e = __builtin_amdgcn_exp2f(x * 2.8853900817779268f); // 2*log2(e)
  return __builtin_fmaf(-2.0f, __builtin_amdgcn_rcpf(1.0f + e), 1.0f);
}
__device__ __forceinline__ float fast_silu(float x) {
  float e = __builtin_amdgcn_exp2f(x * -1.4426950408889634f); // -log2(e)
  return x * __builtin_amdgcn_rcpf(1.0f + e);
}
__device__ __forceinline__ uint32_t pk2(float a, float b) {
  union { f16x2 h; uint32_t u; } c;
  c.h = __builtin_amdgcn_cvt_pkrtz(a, b);
  return c.u;
}
__device__ __forceinline__ f16x8 pack8(f32x4 a, f32x4 b) {
  union { f16x8 v; f16x2 h[4]; } u;
  u.h[0] = __builtin_amdgcn_cvt_pkrtz(a.x, a.y);
  u.h[1] = __builtin_amdgcn_cvt_pkrtz(a.z, a.w);
  u.h[2] = __builtin_amdgcn_cvt_pkrtz(b.x, b.y);
  u.h[3] = __builtin_amdgcn_cvt_pkrtz(b.z, b.w);
  return u.v;
}

// ---------------------------------------------------------------------------
// Kernel 0: zero the loss accumulator slot (d_out is poisoned 0xAA each call)
// ---------------------------------------------------------------------------
__global__ void zero_loss_kernel(float* __restrict__ dout) {
  if (threadIdx.x == 0 && blockIdx.x == 0) dout[LOSSOFF] = 0.0f;
}

// ---------------------------------------------------------------------------
// Kernel 1: repack all weight matrices (stored [K][M] row-major) into
// MFMA A-operand fragment layout, f16:  A[m=lane&15][k=kt*32+(lane>>4)*8+j].
// Frag = 64 lanes x 16B = 1 KB.  Regions by fid:
//   [0,16)  ode_W1^T  (M=128,Kt=2)   [16,48) ode_W2^T (M=128,Kt=4)
//   [48,64) ode_W3^T  (M=64, Kt=4)   [64,80) den_W1^T (M=128,Kt=2)
//   [80,96) den_W2^T  (M=64, Kt=4)   [96,192) proj_W^T (M=64,Kt=24)
// ---------------------------------------------------------------------------
__global__ void pack_kernel(const float* __restrict__ oW1, const float* __restrict__ oW2,
                            const float* __restrict__ oW3, const float* __restrict__ dW1,
                            const float* __restrict__ dW2, const float* __restrict__ pW,
                            char* __restrict__ wdst) {
  int g = blockIdx.x * 256 + threadIdx.x;
  int fid = g >> 6, lane = g & 63;
  if (fid >= 192) return;
  const float* src; int Kt, M, base;
  if      (fid < 16) { src = oW1; Kt = 2;  M = 128; base = 0;  }
  else if (fid < 48) { src = oW2; Kt = 4;  M = 128; base = 16; }
  else if (fid < 64) { src = oW3; Kt = 4;  M = 64;  base = 48; }
  else if (fid < 80) { src = dW1; Kt = 2;  M = 128; base = 64; }
  else if (fid < 96) { src = dW2; Kt = 4;  M = 64;  base = 80; }
  else               { src = pW;  Kt = 24; M = 64;  base = 96; }
  int local = fid - base;
  int mt = local / Kt, kt = local % Kt;
  int m  = mt * 16 + (lane & 15);
  int k0 = kt * 32 + (lane >> 4) * 8;
  f16x8 out;
  #pragma unroll
  for (int j = 0; j < 8; j++) out[j] = (__fp16)src[(size_t)(k0 + j) * M + m];
  *(f16x8*)(wdst + (size_t)(fid * 64 + lane) * 16) = out;
}

// ---------------------------------------------------------------------------
// Kernel 2: prologue.  Per WG: 16 batch rows, 512 threads (8 waves).
// h = bert@projW+b (MFMA, K=768, M-split 4 x K-split 2) -> LN -> +sigma*eps
// -> denoiser (MFMA) -> z_aug -> ws; diff_loss partial -> atomicAdd.
// Activations staged in LDS as [b][units] f16, 16B-chunk XOR-swizzled by b&7.
// ---------------------------------------------------------------------------
__global__ __launch_bounds__(512, 2) void prologue_kernel(
    const float* __restrict__ bert, const float* __restrict__ eps,
    const float* __restrict__ projb, const float* __restrict__ lng,
    const float* __restrict__ lnb,  const float* __restrict__ lns,
    const float* __restrict__ db1,  const float* __restrict__ db2,
    const char* __restrict__ wpack, float* __restrict__ wsz,
    float* __restrict__ dout) {
  __shared__ __attribute__((aligned(16))) char sZ[16 * 128];   // z_noisy f16 [b][64]
  __shared__ __attribute__((aligned(16))) char sH[16 * 256];   // a1 f16 [b][128]
  __shared__ f32x4  sScr[4 * 64];                              // K-split partials
  __shared__ float2 sMV[64];                                   // LN partial sums
  __shared__ float  sLsum[4];

  const int tid  = threadIdx.x;
  const int wave = tid >> 6, lane = tid & 63;
  const int q = lane >> 4, b = lane & 15;
  const int bg = blockIdx.x * 16 + b;
  const int b7 = b & 7;
  const f16x8* wp = (const f16x8*)wpack;
  const int u0 = wave * 16 + q * 4;

  const int zr0 = b * 128 + ((q    ) ^ b7) * 16;
  const int zr1 = b * 128 + ((q + 4) ^ b7) * 16;
  int hr[4];
  #pragma unroll
  for (int s = 0; s < 4; s++) hr[s] = b * 256 + ((4 * s + q) ^ b7) * 16;
  const int hw = b * 256 + (((2 * wave + (q >> 1)) ^ b7) * 16) + (q & 1) * 8;
  const int zw = b * 128 + (((2 * (wave & 3) + (q >> 1)) ^ b7) * 16) + (q & 1) * 8;

  // ---- P1: h^T = projW^T @ bert^T  (M=64 units, N=16 batch, K=768) ----
  const int mt = wave & 3, kh = wave >> 2;
  f32x4 hA = {0,0,0,0}, hB = {0,0,0,0};
  #pragma unroll 4
  for (int i = 0; i < 12; i++) {
    int kt = kh * 12 + i;
    f16x8 af = wp[(size_t)(96 + mt * 24 + kt) * 64 + lane];
    const float* bp = bert + (size_t)bg * 768 + kt * 32 + q * 8;
    f32x4 f0 = *(const f32x4*)bp;
    f32x4 f1 = *(const f32x4*)(bp + 4);
    f16x8 bf = pack8(f0, f1);
    if (i & 1) hB = MFMA(af, bf, hB); else hA = MFMA(af, bf, hA);
  }
  f32x4 hacc = hA + hB;
  if (wave >= 4) sScr[(wave - 4) * 64 + lane] = hacc;
  __syncthreads();

  f32x4 h = {0,0,0,0}, zc = {0,0,0,0};
  if (wave < 4) {
    h = hacc + sScr[wave * 64 + lane];
    h.x += projb[u0 + 0]; h.y += projb[u0 + 1];
    h.z += projb[u0 + 2]; h.w += projb[u0 + 3];
    float s1 = h.x + h.y + h.z + h.w;
    float s2 = h.x*h.x + h.y*h.y + h.z*h.z + h.w*h.w;
    s1 += __shfl_xor(s1, 16); s1 += __shfl_xor(s1, 32);
    s2 += __shfl_xor(s2, 16); s2 += __shfl_xor(s2, 32);
    if (q == 0) sMV[wave * 16 + b] = make_float2(s1, s2);
  }
  __syncthreads();
  if (wave < 4) {
    float t1 = 0.f, t2 = 0.f;
    #pragma unroll
    for (int w2 = 0; w2 < 4; w2++) { float2 m = sMV[w2 * 16 + b]; t1 += m.x; t2 += m.y; }
    float mu  = t1 * (1.0f / 64.0f);
    float var = t2 * (1.0f / 64.0f) - mu * mu;
    float rs  = rsqrtf(var + 1e-5f);
    float sigma = logf(1.0f + expf(lns[0]));        // softplus
    f32x4 e = *(const f32x4*)(eps + (size_t)bg * 64 + u0);
    zc.x = __builtin_fmaf((h.x - mu) * rs, lng[u0+0], lnb[u0+0]);
    zc.y = __builtin_fmaf((h.y - mu) * rs, lng[u0+1], lnb[u0+1]);
    zc.z = __builtin_fmaf((h.z - mu) * rs, lng[u0+2], lnb[u0+2]);
    zc.w = __builtin_fmaf((h.w - mu) * rs, lng[u0+3], lnb[u0+3]);
    f32x4 zn = zc + sigma * e;
    *(uint2*)(sZ + zw) = make_uint2(pk2(zn.x, zn.y), pk2(zn.z, zn.w));
  }
  __syncthreads();
  // ---- den1: a1 = silu(zn @ den_W1 + b1)  (M=128, K=64, all 8 waves) ----
  {
    f16x8 w0 = wp[(size_t)(64 + wave * 2 + 0) * 64 + lane];
    f16x8 w1 = wp[(size_t)(64 + wave * 2 + 1) * 64 + lane];
    f16x8 bz0 = *(const f16x8*)(sZ + zr0);
    f16x8 bz1 = *(const f16x8*)(sZ + zr1);
    f32x4 bias = { db1[u0+0], db1[u0+1], db1[u0+2], db1[u0+3] };
    f32x4 acc = MFMA(w0, bz0, bias);
    acc = MFMA(w1, bz1, acc);
    *(uint2*)(sH + hw) = make_uint2(pk2(fast_silu(acc.x), fast_silu(acc.y)),
                                    pk2(fast_silu(acc.z), fast_silu(acc.w)));
  }
  __syncthreads();
  // ---- den2: z_aug = a1 @ den_W2 + b2 (M=64, K=128, waves 0-3) + loss ----
  if (wave < 4) {
    f16x8 w0 = wp[(size_t)(80 + wave * 4 + 0) * 64 + lane];
    f16x8 w1 = wp[(size_t)(80 + wave * 4 + 1) * 64 + lane];
    f16x8 w2 = wp[(size_t)(80 + wave * 4 + 2) * 64 + lane];
    f16x8 w3 = wp[(size_t)(80 + wave * 4 + 3) * 64 + lane];
    f16x8 g0 = *(const f16x8*)(sH + hr[0]);
    f16x8 g1 = *(const f16x8*)(sH + hr[1]);
    f16x8 g2 = *(const f16x8*)(sH + hr[2]);
    f16x8 g3 = *(const f16x8*)(sH + hr[3]);
    f32x4 bias = { db2[u0+0], db2[u0+1], db2[u0+2], db2[u0+3] };
    const f32x4 z4 = {0,0,0,0};
    f32x4 aA = MFMA(w0, g0, bias); aA = MFMA(w1, g1, aA);
    f32x4 aB = MFMA(w2, g2, z4);   aB = MFMA(w3, g3, aB);
    f32x4 za = aA + aB;
    *(f32x4*)(wsz + (size_t)bg * 64 + u0) = za;          // hand off to ODE kernel
    f32x4 d = za - zc;
    float sl = d.x*d.x + d.y*d.y + d.z*d.z + d.w*d.w;
    const int offs[6] = {1, 2, 4, 8, 16, 32};
    #pragma unroll
    for (int i = 0; i < 6; i++) sl += __shfl_xor(sl, offs[i]);
    if (lane == 0) sLsum[wave] = sl;
  }
  __syncthreads();
  if (tid == 0)
    atomicAdd(dout + LOSSOFF,
              (sLsum[0] + sLsum[1] + sLsum[2] + sLsum[3]) * (1.0f / 262144.0f));
}

// ---------------------------------------------------------------------------
// Kernel 3: ODE scan.  256 WGs x 512 threads, 16 batch rows each, 512 steps.
// Transposed MFMA: weights = A-operand, persistent in VGPRs.  z fp32 in regs
// (waves 0-3 own 16 units each).  3 asm barriers/step.  Wave 4 lanes 0-31
// finalize + store decoded (pred,stop) for the previous step's z.
// ---------------------------------------------------------------------------
__global__ __launch_bounds__(512, 2) void ode_kernel(
    const float* __restrict__ wsz, const char* __restrict__ wpack,
    const float* __restrict__ ob1, const float* __restrict__ ob2,
    const float* __restrict__ ob3, const float* __restrict__ decW,
    const float* __restrict__ decb, float* __restrict__ dout) {
  __shared__ __attribute__((aligned(16))) char sZ [16 * 128];  // z f16 [b][64]
  __shared__ __attribute__((aligned(16))) char sH1[16 * 256];  // tanh1 [b][128]
  __shared__ __attribute__((aligned(16))) char sH2[16 * 256];  // tanh2 [b][128]
  __shared__ float2 sPart[64];                                 // decode partials

  const int tid  = threadIdx.x;
  const int wave = tid >> 6, lane = tid & 63;
  const int q = lane >> 4, b = lane & 15;
  const int bg = blockIdx.x * 16 + b;
  const int b7 = b & 7;
  const f16x8* wp = (const f16x8*)wpack;
  const int u0 = wave * 16 + q * 4;

  const int zr0 = b * 128 + ((q    ) ^ b7) * 16;
  const int zr1 = b * 128 + ((q + 4) ^ b7) * 16;
  int hr[4];
  #pragma unroll
  for (int s = 0; s < 4; s++) hr[s] = b * 256 + ((4 * s + q) ^ b7) * 16;
  const int hw = b * 256 + (((2 * wave + (q >> 1)) ^ b7) * 16) + (q & 1) * 8;
  const int zw = b * 128 + (((2 * (wave & 3) + (q >> 1)) ^ b7) * 16) + (q & 1) * 8;

  // Loop-invariant A-operand weight fragments (VGPR-resident all 512 steps)
  f16x8 a1[2], a2[4], a3[4];
  #pragma unroll
  for (int kt = 0; kt < 2; kt++) a1[kt] = wp[(size_t)(wave * 2 + kt) * 64 + lane];
  #pragma unroll
  for (int kt = 0; kt < 4; kt++) a2[kt] = wp[(size_t)(16 + wave * 4 + kt) * 64 + lane];
  f32x4 b1f = { ob1[u0+0], ob1[u0+1], ob1[u0+2], ob1[u0+3] };
  f32x4 b2f = { ob2[u0+0], ob2[u0+1], ob2[u0+2], ob2[u0+3] };
  f32x4 b3f = {0,0,0,0};
  f32x4 z   = {0,0,0,0};
  float dw0[4] = {0,0,0,0}, dw1[4] = {0,0,0,0};
  if (wave < 4) {
    #pragma unroll
    for (int kt = 0; kt < 4; kt++) a3[kt] = wp[(size_t)(48 + wave * 4 + kt) * 64 + lane];
    b3f.x = ob3[u0+0]; b3f.y = ob3[u0+1]; b3f.z = ob3[u0+2]; b3f.w = ob3[u0+3];
    #pragma unroll
    for (int r = 0; r < 4; r++) { dw0[r] = decW[(u0+r)*2]; dw1[r] = decW[(u0+r)*2+1]; }
    z = *(const f32x4*)(wsz + (size_t)bg * 64 + u0);
  }
  const float decb_c = decb[(lane >> 4) & 1];
  float* const outp = dout + (size_t)((lane >> 4) & 1) * TOTE
                           + (size_t)(blockIdx.x * 16 + (lane & 15)) * OT;
  const float dtc = 1.0f / 512.0f;
  const f32x4 z4 = {0,0,0,0};

  // Pre-loop: publish z_0 (f16) and its decode partials
  if (wave < 4) {
    *(uint2*)(sZ + zw) = make_uint2(pk2(z.x, z.y), pk2(z.z, z.w));
    float pp = z.x*dw0[0]; pp = __builtin_fmaf(z.y, dw0[1], pp);
    pp = __builtin_fmaf(z.z, dw0[2], pp); pp = __builtin_fmaf(z.w, dw0[3], pp);
    float ss = z.x*dw1[0]; ss = __builtin_fmaf(z.y, dw1[1], ss);
    ss = __builtin_fmaf(z.z, dw1[2], ss); ss = __builtin_fmaf(z.w, dw1[3], ss);
    pp += __shfl_xor(pp, 16); pp += __shfl_xor(pp, 32);
    ss += __shfl_xor(ss, 16); ss += __shfl_xor(ss, 32);
    if (q == 0) sPart[wave * 16 + b] = make_float2(pp, ss);
  }
  wg_barrier();

  #pragma unroll 1
  for (int t = 0; t < NT; ++t) {
    // finalize decode for z_t (partials from previous phase), scatter-store
    if (wave == 4 && lane < 32) {
      const int b2 = lane & 15, c = (lane >> 4) & 1;
      const float* pf = (const float*)sPart;
      float s = pf[b2*2+c] + pf[(16+b2)*2+c] + pf[(32+b2)*2+c] + pf[(48+b2)*2+c];
      outp[t] = s + decb_c;
    }
    // stage 1: h1 = tanh(W1^T z + b1)   (all 8 waves, 16 units each)
    f16x8 bz0 = *(const f16x8*)(sZ + zr0);
    f16x8 bz1 = *(const f16x8*)(sZ + zr1);
    f32x4 acc = MFMA(a1[0], bz0, b1f);
    acc = MFMA(a1[1], bz1, acc);
    *(uint2*)(sH1 + hw) = make_uint2(pk2(fast_tanh(acc.x), fast_tanh(acc.y)),
                                     pk2(fast_tanh(acc.z), fast_tanh(acc.w)));
    wg_barrier();
    // stage 2: h2 = tanh(W2^T h1 + b2)  (all 8 waves)
    {
      f16x8 g0 = *(const f16x8*)(sH1 + hr[0]);
      f16x8 g1 = *(const f16x8*)(sH1 + hr[1]);
      f16x8 g2 = *(const f16x8*)(sH1 + hr[2]);
      f16x8 g3 = *(const f16x8*)(sH1 + hr[3]);
      f32x4 aA = MFMA(a2[0], g0, b2f); aA = MFMA(a2[1], g1, aA);
      f32x4 aB = MFMA(a2[2], g2, z4); aB = MFMA(a2[3], g3, aB);
      f32x4 hv = aA + aB;
      *(uint2*)(sH2 + hw) = make_uint2(pk2(fast_tanh(hv.x), fast_tanh(hv.y)),
                                       pk2(fast_tanh(hv.z), fast_tanh(hv.w)));
    }
    wg_barrier();
    // stage 3: f = W3^T h2 + b3; z += dt*f; publish z f16 + decode partials
    if (wave < 4) {
      f16x8 g0 = *(const f16x8*)(sH2 + hr[0]);
      f16x8 g1 = *(const f16x8*)(sH2 + hr[1]);
      f16x8 g2 = *(const f16x8*)(sH2 + hr[2]);
      f16x8 g3 = *(const f16x8*)(sH2 + hr[3]);
      f32x4 fA = MFMA(a3[0], g0, b3f); fA = MFMA(a3[1], g1, fA);
      f32x4 fB = MFMA(a3[2], g2, z4); fB = MFMA(a3[3], g3, fB);
      f32x4 f = fA + fB;
      z.x = __builtin_fmaf(dtc, f.x, z.x);
      z.y = __builtin_fmaf(dtc, f.y, z.y);
      z.z = __builtin_fmaf(dtc, f.z, z.z);
      z.w = __builtin_fmaf(dtc, f.w, z.w);
      *(uint2*)(sZ + zw) = make_uint2(pk2(z.x, z.y), pk2(z.z, z.w));
      float pp = z.x*dw0[0]; pp = __builtin_fmaf(z.y, dw0[1], pp);
      pp = __builtin_fmaf(z.z, dw0[2], pp); pp = __builtin_fmaf(z.w, dw0[3], pp);
      float ss = z.x*dw1[0]; ss = __builtin_fmaf(z.y, dw1[1], ss);
      ss = __builtin_fmaf(z.z, dw1[2], ss); ss = __builtin_fmaf(z.w, dw1[3], ss);
      pp += __shfl_xor(pp, 16); pp += __shfl_xor(pp, 32);
      ss += __shfl_xor(ss, 16); ss += __shfl_xor(ss, 32);
      if (q == 0) sPart[wave * 16 + b] = make_float2(pp, ss);
    }
    wg_barrier();
  }
  // final decode for z_512
  if (wave == 4 && lane < 32) {
    const int b2 = lane & 15, c = (lane >> 4) & 1;
    const float* pf = (const float*)sPart;
    float s = pf[b2*2+c] + pf[(16+b2)*2+c] + pf[(32+b2)*2+c] + pf[(48+b2)*2+c];
    outp[NT] = s + decb_c;
  }
}

// ---------------------------------------------------------------------------
extern "C" void kernel_launch(void* const* d_in, const int* in_sizes, int n_in,
                              void* d_out, int out_size, void* d_ws, size_t ws_size,
                              hipStream_t stream) {
  const float* bert  = (const float*)d_in[0];
  // d_in[1] times, d_in[2] seq_lens: unused by the math
  const float* eps   = (const float*)d_in[3];
  const float* projW = (const float*)d_in[4];
  const float* projb = (const float*)d_in[5];
  const float* lng   = (const float*)d_in[6];
  const float* lnb   = (const float*)d_in[7];
  const float* lns   = (const float*)d_in[8];
  const float* denW1 = (const float*)d_in[9];
  const float* denb1 = (const float*)d_in[10];
  const float* denW2 = (const float*)d_in[11];
  const float* denb2 = (const float*)d_in[12];
  const float* odeW1 = (const float*)d_in[13];
  const float* odeb1 = (const float*)d_in[14];
  const float* odeW2 = (const float*)d_in[15];
  const float* odeb2 = (const float*)d_in[16];
  const float* odeW3 = (const float*)d_in[17];
  const float* odeb3 = (const float*)d_in[18];
  const float* decW  = (const float*)d_in[19];
  const float* decb  = (const float*)d_in[20];
  float* dout = (float*)d_out;

  float* wsz  = (float*)d_ws;                       // z_aug: 4096*64 f32 = 1 MB
  char*  wpak = (char*)d_ws + (1u << 20);           // packed frags: 192 KB

  zero_loss_kernel<<<1, 64, 0, stream>>>(dout);
  pack_kernel<<<48, 256, 0, stream>>>(odeW1, odeW2, odeW3, denW1, denW2, projW, wpak);
  prologue_kernel<<<256, 512, 0, stream>>>(bert, eps, projb, lng, lnb, lns,
                                           denb1, denb2, wpak, wsz, dout);
  ode_kernel<<<256, 512, 0, stream>>>(wsz, wpak, odeb1, odeb2, odeb3, decW, decb, dout);
}